// Round 1
// baseline (1516.843 us; speedup 1.0000x reference)
//
#include <hip/hip_runtime.h>
#include <hip/hip_bf16.h>

typedef unsigned short u16;
typedef unsigned int u32;
typedef __attribute__((ext_vector_type(4))) float f32x4;
typedef __attribute__((ext_vector_type(8))) short bf16x8;

#define DEV static __device__ __forceinline__

DEV float bf2f(u16 u) { u32 x = ((u32)u) << 16; return __builtin_bit_cast(float, x); }
DEV u16 f2bf(float f) {
  __hip_bfloat16 h = __float2bfloat16(f);
  return __builtin_bit_cast(u16, h);
}

// ---------------------------------------------------------------- convert
__global__ void cvt_bf16(const float* __restrict__ s, u16* __restrict__ d, int n) {
  int i = blockIdx.x * 256 + threadIdx.x;
  if (i < n) d[i] = f2bf(s[i]);
}

// ---------------------------------------------------------------- layernorm (one wave per 512-row, bf16 out)
__global__ __launch_bounds__(256)
void ln_bf16(const float* __restrict__ src, const float* __restrict__ g,
             const float* __restrict__ b, u16* __restrict__ dst) {
  const int row = blockIdx.x * 4 + (threadIdx.x >> 6);
  const int lane = threadIdx.x & 63;
  const float* p = src + (long)row * 512 + lane * 8;
  float x[8];
  *(float4*)&x[0] = *(const float4*)p;
  *(float4*)&x[4] = *(const float4*)(p + 4);
  float s = 0.f;
#pragma unroll
  for (int e = 0; e < 8; ++e) s += x[e];
#pragma unroll
  for (int off = 32; off; off >>= 1) s += __shfl_xor(s, off, 64);
  const float mean = s * (1.0f / 512.0f);
  float q = 0.f;
#pragma unroll
  for (int e = 0; e < 8; ++e) { float d = x[e] - mean; q += d * d; }
#pragma unroll
  for (int off = 32; off; off >>= 1) q += __shfl_xor(q, off, 64);
  const float rinv = rsqrtf(q * (1.0f / 512.0f) + 1e-5f);
  u16 o[8];
  const int c0 = lane * 8;
#pragma unroll
  for (int e = 0; e < 8; ++e) o[e] = f2bf((x[e] - mean) * rinv * g[c0 + e] + b[c0 + e]);
  *(uint4*)(dst + (long)row * 512 + c0) = *(uint4*)o;
}

// ---------------------------------------------------------------- GEMM (NT): C[m,n] = sum_k A[m,k]*W[n,k] + bias, + epilogue
// A: [M,K] bf16 row-major; W: [N,K] bf16 row-major. M,N %128==0, K %32==0.
constexpr int BM = 128, BN = 128, BK = 32, LDT = 40;  // LDT=40: odd*8 stride kills 8-way LDS conflicts

enum { EPI_QKV = 0, EPI_PROJ = 1, EPI_GELU = 2, EPI_FC2 = 3 };

template <int EPI>
__global__ __launch_bounds__(256)
void gemm_nt(const u16* __restrict__ A, const u16* __restrict__ W,
             const float* __restrict__ bias, const float* __restrict__ res,
             void* __restrict__ outv, int M, int N, int K) {
  __shared__ u16 As[BM * LDT];
  __shared__ u16 Bs[BN * LDT];
  const int t = threadIdx.x;
  const int lane = t & 63;
  const int wave = t >> 6;
  const int wm = (wave >> 1) * 64;
  const int wn = (wave & 1) * 64;
  const long m0 = (long)blockIdx.y * BM;
  const long n0 = (long)blockIdx.x * BN;

  const int srow = t >> 2;  // 0..63 ; covers rows srow and srow+64
  const int sch = t & 3;    // 4 x 16B chunks per 64B row
  const u16* gA = A + (m0 + srow) * (long)K + sch * 8;
  const u16* gB = W + (n0 + srow) * (long)K + sch * 8;

  f32x4 acc[4][4] = {};

  for (int k0 = 0; k0 < K; k0 += BK) {
    uint4 a0 = *(const uint4*)(gA + k0);
    uint4 a1 = *(const uint4*)(gA + k0 + 64L * K);
    uint4 b0 = *(const uint4*)(gB + k0);
    uint4 b1 = *(const uint4*)(gB + k0 + 64L * K);
    *(uint4*)&As[srow * LDT + sch * 8] = a0;
    *(uint4*)&As[(srow + 64) * LDT + sch * 8] = a1;
    *(uint4*)&Bs[srow * LDT + sch * 8] = b0;
    *(uint4*)&Bs[(srow + 64) * LDT + sch * 8] = b1;
    __syncthreads();
    const int fr = lane & 15, koff = (lane >> 4) * 8;
    bf16x8 af[4], bff[4];
#pragma unroll
    for (int i = 0; i < 4; ++i) af[i] = *(const bf16x8*)&As[(wm + i * 16 + fr) * LDT + koff];
#pragma unroll
    for (int j = 0; j < 4; ++j) bff[j] = *(const bf16x8*)&Bs[(wn + j * 16 + fr) * LDT + koff];
#pragma unroll
    for (int i = 0; i < 4; ++i)
#pragma unroll
      for (int j = 0; j < 4; ++j)
        acc[i][j] = __builtin_amdgcn_mfma_f32_16x16x32_bf16(af[i], bff[j], acc[i][j], 0, 0, 0);
    __syncthreads();
  }

  // C/D layout (m89-verified): col = lane&15, row = (lane>>4)*4 + reg
  const int col = lane & 15;
  const int rq = (lane >> 4) * 4;
#pragma unroll
  for (int i = 0; i < 4; ++i) {
#pragma unroll
    for (int j = 0; j < 4; ++j) {
#pragma unroll
      for (int r = 0; r < 4; ++r) {
        const long m = m0 + wm + i * 16 + rq + r;
        const long n = n0 + wn + j * 16 + col;
        const float v = acc[i][j][r] + bias[n];
        const long idx = m * (long)N + n;
        if constexpr (EPI == EPI_QKV) {
          ((u16*)outv)[idx] = f2bf(v);
        } else if constexpr (EPI == EPI_PROJ) {
          ((float*)outv)[idx] = v + res[idx];
        } else if constexpr (EPI == EPI_GELU) {
          ((u16*)outv)[idx] = f2bf(0.5f * v * (1.0f + erff(v * 0.70710678118f)));
        } else {  // EPI_FC2
          ((float*)outv)[idx] = v + res[idx];
        }
      }
    }
  }
}

// ---------------------------------------------------------------- windowed attention, one block per (window, head)
constexpr int QP = 36, SP = 65;  // padded LDS strides

__global__ __launch_bounds__(256)
void attn_win(const u16* __restrict__ qkv, const float* __restrict__ mmap,
              const float* __restrict__ rpb, u16* __restrict__ outp) {
  __shared__ float q[64 * QP], k[64 * QP], v[64 * QP];
  __shared__ float S[64 * SP];
  __shared__ float mw[64];
  __shared__ int tok[64], regi[64];
  const int t = threadIdx.x;
  const int head = blockIdx.x & 15;
  const int win = blockIdx.x >> 4;
  const int b = win >> 6, wh = (win >> 3) & 7, ww = win & 7;

  if (t < 64) {
    const int i = t >> 3, j = t & 7;
    const int hs = wh * 8 + i, wsv = ww * 8 + j;   // shifted-frame coords
    const int h = (hs + 4) & 63, w = (wsv + 4) & 63;  // original coords (roll by -shift)
    const int tk = b * 4096 + h * 64 + w;
    tok[t] = tk;
    mw[t] = fminf(fmaxf(mmap[tk], 0.0f), 1.0f);
    const int rh = hs < 56 ? 0 : (hs < 60 ? 1 : 2);
    const int rw = wsv < 56 ? 0 : (wsv < 60 ? 1 : 2);
    regi[t] = rh * 3 + rw;
  }
  __syncthreads();

  for (int id = t; id < 2048; id += 256) {
    const int n = id >> 5, d = id & 31;
    const long base = (long)tok[n] * 1536 + head * 32 + d;
    q[n * QP + d] = bf2f(qkv[base]);
    k[n * QP + d] = bf2f(qkv[base + 512]);
    v[n * QP + d] = bf2f(qkv[base + 1024]);
  }
  __syncthreads();

  // scores: thread t -> row n = t>>2, 16 columns starting (t&3)*16 (rotated by n for bank spread)
  {
    const int n = t >> 2, ms0 = (t & 3) * 16;
    const int in_ = n >> 3, jn = n & 7;
    float4 qr[8];
#pragma unroll
    for (int c = 0; c < 8; ++c) qr[c] = *(const float4*)&q[n * QP + c * 4];
    const float mwn = mw[n];
    const int rn = regi[n];
    const float scale = 0.1767766952966369f;  // 1/sqrt(32)
    for (int mi = 0; mi < 16; ++mi) {
      const int m = ms0 + ((mi + n) & 15);
      float s = 0.f;
#pragma unroll
      for (int c = 0; c < 8; ++c) {
        const float4 kv = *(const float4*)&k[m * QP + c * 4];
        s += qr[c].x * kv.x + qr[c].y * kv.y + qr[c].z * kv.z + qr[c].w * kv.w;
      }
      const int im = m >> 3, jm = m & 7;
      s = s * scale + rpb[((in_ - im + 7) * 15 + (jn - jm + 7)) * 16 + head] + 0.5f * (mwn + mw[m]);
      if (rn != regi[m]) s -= 100.0f;
      S[n * SP + m] = s;
    }
  }
  __syncthreads();

  if (t < 64) {
    float mx = -1e30f;
    for (int m = 0; m < 64; ++m) mx = fmaxf(mx, S[t * SP + m]);
    float sum = 0.f;
    for (int m = 0; m < 64; ++m) { const float e = __expf(S[t * SP + m] - mx); S[t * SP + m] = e; sum += e; }
    const float r = 1.0f / sum;
    for (int m = 0; m < 64; ++m) S[t * SP + m] *= r;
  }
  __syncthreads();

  // PV: thread t -> row n = t>>2, 8 dims starting (t&3)*8 ; scatter to original token layout
  {
    const int n = t >> 2, d0 = (t & 3) * 8;
    float acc[8] = {};
    for (int m = 0; m < 64; ++m) {
      const float s = S[n * SP + m];
      const float4 v0 = *(const float4*)&v[m * QP + d0];
      const float4 v1 = *(const float4*)&v[m * QP + d0 + 4];
      acc[0] += s * v0.x; acc[1] += s * v0.y; acc[2] += s * v0.z; acc[3] += s * v0.w;
      acc[4] += s * v1.x; acc[5] += s * v1.y; acc[6] += s * v1.z; acc[7] += s * v1.w;
    }
    u16 o[8];
#pragma unroll
    for (int e = 0; e < 8; ++e) o[e] = f2bf(acc[e]);
    *(uint4*)(outp + (long)tok[n] * 512 + head * 32 + d0) = *(uint4*)o;
  }
}

// ---------------------------------------------------------------- launch
extern "C" void kernel_launch(void* const* d_in, const int* in_sizes, int n_in,
                              void* d_out, int out_size, void* d_ws, size_t ws_size,
                              hipStream_t stream) {
  (void)in_sizes; (void)n_in; (void)out_size; (void)ws_size;
  const float* x      = (const float*)d_in[0];
  const float* mmap   = (const float*)d_in[1];
  const float* n1g    = (const float*)d_in[2];
  const float* n1b    = (const float*)d_in[3];
  const float* qkv_w  = (const float*)d_in[4];
  const float* qkv_b  = (const float*)d_in[5];
  const float* proj_w = (const float*)d_in[6];
  const float* proj_b = (const float*)d_in[7];
  const float* rpb    = (const float*)d_in[8];
  const float* n2g    = (const float*)d_in[9];
  const float* n2b    = (const float*)d_in[10];
  const float* fc1_w  = (const float*)d_in[11];
  const float* fc1_b  = (const float*)d_in[12];
  const float* fc2_w  = (const float*)d_in[13];
  const float* fc2_b  = (const float*)d_in[14];
  float* out = (float*)d_out;
  char* ws = (char*)d_ws;

  // workspace layout (total ~454 MB)
  u16*   ybf   = (u16*)(ws);                  // 64 MB : LN1 out, later LN2 out
  u16*   qkvbf = (u16*)(ws + (64L  << 20));   // 192 MB
  u16*   attno = (u16*)(ws + (256L << 20));   // 64 MB
  float* x1    = (float*)(ws + (320L << 20)); // 128 MB
  u16*   hbuf  = qkvbf;                       // 256 MB, reuses qkvbf+attno region
  u16*   wqkv  = (u16*)(ws + (448L << 20));
  u16*   wproj = wqkv + 1536 * 512;
  u16*   wfc1  = wproj + 512 * 512;
  u16*   wfc2  = wfc1 + 2048 * 512;

  cvt_bf16<<<1536 * 512 / 256, 256, 0, stream>>>(qkv_w, wqkv, 1536 * 512);
  cvt_bf16<<<512 * 512 / 256, 256, 0, stream>>>(proj_w, wproj, 512 * 512);
  cvt_bf16<<<2048 * 512 / 256, 256, 0, stream>>>(fc1_w, wfc1, 2048 * 512);
  cvt_bf16<<<512 * 2048 / 256, 256, 0, stream>>>(fc2_w, wfc2, 512 * 2048);

  ln_bf16<<<16384, 256, 0, stream>>>(x, n1g, n1b, ybf);
  gemm_nt<EPI_QKV><<<dim3(12, 512), 256, 0, stream>>>(ybf, wqkv, qkv_b, nullptr, qkvbf, 65536, 1536, 512);
  attn_win<<<16384, 256, 0, stream>>>(qkvbf, mmap, rpb, attno);
  gemm_nt<EPI_PROJ><<<dim3(4, 512), 256, 0, stream>>>(attno, wproj, proj_b, x, x1, 65536, 512, 512);
  ln_bf16<<<16384, 256, 0, stream>>>(x1, n2g, n2b, ybf);
  gemm_nt<EPI_GELU><<<dim3(16, 512), 256, 0, stream>>>(ybf, wfc1, fc1_b, nullptr, hbuf, 65536, 2048, 512);
  gemm_nt<EPI_FC2><<<dim3(4, 512), 256, 0, stream>>>(hbuf, wfc2, fc2_b, x1, out, 65536, 512, 2048);
}

// Round 2
// 1202.002 us; speedup vs baseline: 1.2619x; 1.2619x over previous
//
#include <hip/hip_runtime.h>
#include <hip/hip_bf16.h>

typedef unsigned short u16;
typedef unsigned int u32;
typedef __attribute__((ext_vector_type(4))) float f32x4;
typedef __attribute__((ext_vector_type(8))) short bf16x8;

#define DEV static __device__ __forceinline__

DEV float bf2f(u16 u) { u32 x = ((u32)u) << 16; return __builtin_bit_cast(float, x); }
DEV u16 f2bf(float f) {
  __hip_bfloat16 h = __float2bfloat16(f);
  return __builtin_bit_cast(u16, h);
}

DEV void gld16(const u16* g, u16* l) {
  __builtin_amdgcn_global_load_lds((const __attribute__((address_space(1))) void*)g,
                                   (__attribute__((address_space(3))) void*)l, 16, 0, 0);
}

// ---------------------------------------------------------------- convert
__global__ void cvt_bf16(const float* __restrict__ s, u16* __restrict__ d, int n) {
  int i = blockIdx.x * 256 + threadIdx.x;
  if (i < n) d[i] = f2bf(s[i]);
}

// ---------------------------------------------------------------- layernorm (one wave per 512-row, bf16 out)
__global__ __launch_bounds__(256)
void ln_bf16(const float* __restrict__ src, const float* __restrict__ g,
             const float* __restrict__ b, u16* __restrict__ dst) {
  const int row = blockIdx.x * 4 + (threadIdx.x >> 6);
  const int lane = threadIdx.x & 63;
  const float* p = src + (long)row * 512 + lane * 8;
  float x[8];
  *(float4*)&x[0] = *(const float4*)p;
  *(float4*)&x[4] = *(const float4*)(p + 4);
  float s = 0.f;
#pragma unroll
  for (int e = 0; e < 8; ++e) s += x[e];
#pragma unroll
  for (int off = 32; off; off >>= 1) s += __shfl_xor(s, off, 64);
  const float mean = s * (1.0f / 512.0f);
  float q = 0.f;
#pragma unroll
  for (int e = 0; e < 8; ++e) { float d = x[e] - mean; q += d * d; }
#pragma unroll
  for (int off = 32; off; off >>= 1) q += __shfl_xor(q, off, 64);
  const float rinv = rsqrtf(q * (1.0f / 512.0f) + 1e-5f);
  u16 o[8];
  const int c0 = lane * 8;
#pragma unroll
  for (int e = 0; e < 8; ++e) o[e] = f2bf((x[e] - mean) * rinv * g[c0 + e] + b[c0 + e]);
  *(uint4*)(dst + (long)row * 512 + c0) = *(uint4*)o;
}

// ---------------------------------------------------------------- GEMM (NT), m97-style global_load_lds staging
constexpr int BM = 128, BN = 128, BK = 32;

enum { EPI_QKV = 0, EPI_PROJ = 1, EPI_GELU = 2, EPI_FC2 = 3 };

template <int EPI>
__global__ __launch_bounds__(256)
void gemm_nt(const u16* __restrict__ A, const u16* __restrict__ W,
             const float* __restrict__ bias, const float* __restrict__ res,
             void* __restrict__ outv, int M, int N, int K) {
  __shared__ u16 As[BM * BK];
  __shared__ u16 Bs[BN * BK];
  const int t = threadIdx.x;
  const int lane = t & 63;
  const int wave = t >> 6;
  const int wm = (wave >> 1) * 64;
  const int wn = (wave & 1) * 64;
  const long m0 = (long)blockIdx.y * BM;
  const long n0 = (long)blockIdx.x * BN;

  // staging: chunk = c*4 + wave (1 KB each); lane l -> row chunk*16 + (l>>2), 16B piece (l&3)
  const int r0 = wave * 16 + (lane >> 2);
  const int kel = (lane & 3) * 8;
  const u16* gA0 = A + (m0 + r0) * (long)K + kel;
  const u16* gA1 = gA0 + 64L * K;
  const u16* gB0 = W + (n0 + r0) * (long)K + kel;
  const u16* gB1 = gB0 + 64L * K;
  u16* lA0 = As + wave * 512;
  u16* lA1 = As + (4 + wave) * 512;
  u16* lB0 = Bs + wave * 512;
  u16* lB1 = Bs + (4 + wave) * 512;

  f32x4 acc[4][4] = {};
  const int fr = lane & 15, koff = (lane >> 4) * 8;

  for (int k0 = 0; k0 < K; k0 += BK) {
    gld16(gA0 + k0, lA0);
    gld16(gA1 + k0, lA1);
    gld16(gB0 + k0, lB0);
    gld16(gB1 + k0, lB1);
    __syncthreads();
    bf16x8 af[4], bff[4];
#pragma unroll
    for (int i = 0; i < 4; ++i) af[i] = *(const bf16x8*)&As[(wm + i * 16 + fr) * BK + koff];
#pragma unroll
    for (int j = 0; j < 4; ++j) bff[j] = *(const bf16x8*)&Bs[(wn + j * 16 + fr) * BK + koff];
#pragma unroll
    for (int i = 0; i < 4; ++i)
#pragma unroll
      for (int j = 0; j < 4; ++j)
        acc[i][j] = __builtin_amdgcn_mfma_f32_16x16x32_bf16(af[i], bff[j], acc[i][j], 0, 0, 0);
    __syncthreads();
  }

  // C/D layout: col = lane&15, row = (lane>>4)*4 + reg
  const int col = lane & 15;
  const int rq = (lane >> 4) * 4;
#pragma unroll
  for (int i = 0; i < 4; ++i) {
#pragma unroll
    for (int j = 0; j < 4; ++j) {
#pragma unroll
      for (int r = 0; r < 4; ++r) {
        const long m = m0 + wm + i * 16 + rq + r;
        const long n = n0 + wn + j * 16 + col;
        const float v = acc[i][j][r] + bias[n];
        const long idx = m * (long)N + n;
        if constexpr (EPI == EPI_QKV) {
          ((u16*)outv)[idx] = f2bf(v);
        } else if constexpr (EPI == EPI_PROJ) {
          ((float*)outv)[idx] = v + res[idx];
        } else if constexpr (EPI == EPI_GELU) {
          ((u16*)outv)[idx] = f2bf(0.5f * v * (1.0f + erff(v * 0.70710678118f)));
        } else {  // EPI_FC2
          ((float*)outv)[idx] = v + res[idx];
        }
      }
    }
  }
}

// ---------------------------------------------------------------- MFMA windowed attention
// one block per window; 4 waves x 4 heads each
constexpr int SS_S = 68;  // S^T stride (elems); 8B-aligned b64 writes
constexpr int VT_S = 72;  // V^T stride (elems); 16B-aligned b128 reads

__global__ __launch_bounds__(256)
void attn_mfma(const u16* __restrict__ qkv, const float* __restrict__ mmap,
               const float* __restrict__ rpb, u16* __restrict__ outp) {
  __shared__ u16 SSb[4 * 64 * SS_S];   // 34816 B
  __shared__ u16 Vtb[4 * 32 * VT_S];   // 18432 B
  __shared__ u16 rpb_s[16 * 226];      // 7232 B
  __shared__ float mw[64];
  __shared__ int tok[64];
  __shared__ int regi[64];

  const int t = threadIdx.x;
  const int lane = t & 63, wave = t >> 6;
  const int c = lane & 15, q = lane >> 4;
  const int win = blockIdx.x;
  const int b = win >> 6, wh = (win >> 3) & 7, ww = win & 7;

  if (t < 64) {
    const int i = t >> 3, j = t & 7;
    const int hs = wh * 8 + i, wsv = ww * 8 + j;       // shifted-frame coords
    const int h = (hs + 4) & 63, w = (wsv + 4) & 63;   // original coords
    const int tk = b * 4096 + h * 64 + w;
    tok[t] = tk;
    mw[t] = fminf(fmaxf(mmap[tk], 0.f), 1.f);
    regi[t] = (hs < 56 ? 0 : (hs < 60 ? 1 : 2)) * 3 + (wsv < 56 ? 0 : (wsv < 60 ? 1 : 2));
  }
  for (int id = t; id < 3600; id += 256) {
    const int h = id & 15, idx = id >> 4;
    rpb_s[h * 226 + idx] = f2bf(rpb[id]);
  }
  __syncthreads();

  u16* SS = SSb + wave * 64 * SS_S;
  u16* Vt = Vtb + wave * 32 * VT_S;

  // hoisted per-lane state
  int tQ[4];
  float mwn[16], mwm[4];
  int rgn[16], rgm[4];
#pragma unroll
  for (int i = 0; i < 4; ++i) tQ[i] = tok[16 * i + c];
#pragma unroll
  for (int i = 0; i < 4; ++i)
#pragma unroll
    for (int r = 0; r < 4; ++r) {
      const int n = 16 * i + 4 * q + r;
      mwn[i * 4 + r] = mw[n];
      rgn[i * 4 + r] = regi[n];
    }
#pragma unroll
  for (int j = 0; j < 4; ++j) {
    const int m = 16 * j + c;
    mwm[j] = mw[m];
    rgm[j] = regi[m];
  }
  const int imc = c >> 3, jmc = c & 7;  // col m = 16j+c: im = 2j+imc, jm = jmc
  const int tV = tok[lane];
  const float scale = 0.17677669529663687f;  // 1/sqrt(32)

  for (int hi = 0; hi < 4; ++hi) {
    const int head = wave * 4 + hi;

    // Q/K fragments: A/B layout [m=lane&15][k=q*8+j], direct from global
    bf16x8 qf[4], kf[4];
#pragma unroll
    for (int i = 0; i < 4; ++i) {
      const u16* base = qkv + (long)tQ[i] * 1536 + head * 32 + q * 8;
      qf[i] = *(const bf16x8*)(base);
      kf[i] = *(const bf16x8*)(base + 512);
    }

    // stage V transposed: Vt[d][token]
    {
      const u16* vp = qkv + (long)tV * 1536 + 1024 + head * 32;
      u16 vv[32];
      *(uint4*)&vv[0]  = *(const uint4*)(vp);
      *(uint4*)&vv[8]  = *(const uint4*)(vp + 8);
      *(uint4*)&vv[16] = *(const uint4*)(vp + 16);
      *(uint4*)&vv[24] = *(const uint4*)(vp + 24);
#pragma unroll
      for (int d = 0; d < 32; ++d) Vt[d * VT_S + lane] = vv[d];
    }

    // QK^T: S[n][m], tiles i (rows n), j (cols m)
    f32x4 acc[4][4] = {};
#pragma unroll
    for (int i = 0; i < 4; ++i)
#pragma unroll
      for (int j = 0; j < 4; ++j)
        acc[i][j] = __builtin_amdgcn_mfma_f32_16x16x32_bf16(qf[i], kf[j], acc[i][j], 0, 0, 0);

    // bias + softmax in registers (lane holds rows n=16i+4q+r, cols m=16j+c)
    const u16* rb = rpb_s + head * 226;
    float rmx[16], rsum[16];
#pragma unroll
    for (int i = 0; i < 4; ++i)
#pragma unroll
      for (int r = 0; r < 4; ++r) {
        const int n = 16 * i + 4 * q + r;
        const int inr = n >> 3, jnr = n & 7;
        float mx = -1e30f;
#pragma unroll
        for (int j = 0; j < 4; ++j) {
          const int di = inr - 2 * j - imc + 7;
          const int dj = jnr - jmc + 7;
          float s = acc[i][j][r] * scale + bf2f(rb[di * 15 + dj]) +
                    0.5f * (mwn[i * 4 + r] + mwm[j]);
          if (rgn[i * 4 + r] != rgm[j]) s -= 100.f;
          acc[i][j][r] = s;
          mx = fmaxf(mx, s);
        }
        rmx[i * 4 + r] = mx;
      }
#pragma unroll
    for (int ir = 0; ir < 16; ++ir)
#pragma unroll
      for (int msk = 1; msk < 16; msk <<= 1)
        rmx[ir] = fmaxf(rmx[ir], __shfl_xor(rmx[ir], msk, 64));
#pragma unroll
    for (int i = 0; i < 4; ++i)
#pragma unroll
      for (int r = 0; r < 4; ++r) {
        float sm = 0.f;
#pragma unroll
        for (int j = 0; j < 4; ++j) {
          const float e = __expf(acc[i][j][r] - rmx[i * 4 + r]);
          acc[i][j][r] = e;
          sm += e;
        }
        rsum[i * 4 + r] = sm;
      }
#pragma unroll
    for (int ir = 0; ir < 16; ++ir) {
#pragma unroll
      for (int msk = 1; msk < 16; msk <<= 1)
        rsum[ir] += __shfl_xor(rsum[ir], msk, 64);
      rsum[ir] = 1.0f / rsum[ir];
    }

    // write SS = S^T (bf16), packed b64: SS[m][n..n+3]
#pragma unroll
    for (int i = 0; i < 4; ++i)
#pragma unroll
      for (int j = 0; j < 4; ++j) {
        ushort4 pk;
        pk.x = f2bf(acc[i][j][0] * rsum[i * 4 + 0]);
        pk.y = f2bf(acc[i][j][1] * rsum[i * 4 + 1]);
        pk.z = f2bf(acc[i][j][2] * rsum[i * 4 + 2]);
        pk.w = f2bf(acc[i][j][3] * rsum[i * 4 + 3]);
        *(ushort4*)&SS[(16 * j + c) * SS_S + 16 * i + 4 * q] = pk;
      }

    __syncthreads();  // writes (Vt, SS) -> reads, all waves in lockstep

    // PV: O^T = Vt(32x64) * S^T(64x64)
    bf16x8 av[2][2];
#pragma unroll
    for (int mi = 0; mi < 2; ++mi)
#pragma unroll
      for (int ki = 0; ki < 2; ++ki)
        av[mi][ki] = *(const bf16x8*)&Vt[(16 * mi + c) * VT_S + 32 * ki + 8 * q];

    f32x4 oacc[2][4] = {};
#pragma unroll
    for (int ki = 0; ki < 2; ++ki)
#pragma unroll
      for (int ni = 0; ni < 4; ++ni) {
        union { u16 h[8]; bf16x8 v; } ub;
#pragma unroll
        for (int jj = 0; jj < 8; ++jj)
          ub.h[jj] = SS[(32 * ki + 8 * q + jj) * SS_S + 16 * ni + c];
#pragma unroll
        for (int mi = 0; mi < 2; ++mi)
          oacc[mi][ni] = __builtin_amdgcn_mfma_f32_16x16x32_bf16(av[mi][ki], ub.v, oacc[mi][ni], 0, 0, 0);
      }

    // store O: D col = token n = 16ni+c, row = d = 16mi+4q+r (r contiguous -> 8B stores)
#pragma unroll
    for (int ni = 0; ni < 4; ++ni) {
      u16* ob = outp + (long)tQ[ni] * 512 + head * 32;
#pragma unroll
      for (int mi = 0; mi < 2; ++mi) {
        ushort4 pk;
        pk.x = f2bf(oacc[mi][ni][0]);
        pk.y = f2bf(oacc[mi][ni][1]);
        pk.z = f2bf(oacc[mi][ni][2]);
        pk.w = f2bf(oacc[mi][ni][3]);
        *(ushort4*)(ob + 16 * mi + 4 * q) = pk;
      }
    }
    __syncthreads();  // reads done before next iteration's writes
  }
}

// ---------------------------------------------------------------- launch
extern "C" void kernel_launch(void* const* d_in, const int* in_sizes, int n_in,
                              void* d_out, int out_size, void* d_ws, size_t ws_size,
                              hipStream_t stream) {
  (void)in_sizes; (void)n_in; (void)out_size; (void)ws_size;
  const float* x      = (const float*)d_in[0];
  const float* mmap   = (const float*)d_in[1];
  const float* n1g    = (const float*)d_in[2];
  const float* n1b    = (const float*)d_in[3];
  const float* qkv_w  = (const float*)d_in[4];
  const float* qkv_b  = (const float*)d_in[5];
  const float* proj_w = (const float*)d_in[6];
  const float* proj_b = (const float*)d_in[7];
  const float* rpb    = (const float*)d_in[8];
  const float* n2g    = (const float*)d_in[9];
  const float* n2b    = (const float*)d_in[10];
  const float* fc1_w  = (const float*)d_in[11];
  const float* fc1_b  = (const float*)d_in[12];
  const float* fc2_w  = (const float*)d_in[13];
  const float* fc2_b  = (const float*)d_in[14];
  float* out = (float*)d_out;
  char* ws = (char*)d_ws;

  u16*   ybf   = (u16*)(ws);                  // 64 MB : LN1 out, later LN2 out
  u16*   qkvbf = (u16*)(ws + (64L  << 20));   // 192 MB
  u16*   attno = (u16*)(ws + (256L << 20));   // 64 MB
  float* x1    = (float*)(ws + (320L << 20)); // 128 MB
  u16*   hbuf  = qkvbf;                       // 256 MB, reuses qkvbf+attno region
  u16*   wqkv  = (u16*)(ws + (448L << 20));
  u16*   wproj = wqkv + 1536 * 512;
  u16*   wfc1  = wproj + 512 * 512;
  u16*   wfc2  = wfc1 + 2048 * 512;

  cvt_bf16<<<1536 * 512 / 256, 256, 0, stream>>>(qkv_w, wqkv, 1536 * 512);
  cvt_bf16<<<512 * 512 / 256, 256, 0, stream>>>(proj_w, wproj, 512 * 512);
  cvt_bf16<<<2048 * 512 / 256, 256, 0, stream>>>(fc1_w, wfc1, 2048 * 512);
  cvt_bf16<<<512 * 2048 / 256, 256, 0, stream>>>(fc2_w, wfc2, 512 * 2048);

  ln_bf16<<<16384, 256, 0, stream>>>(x, n1g, n1b, ybf);
  gemm_nt<EPI_QKV><<<dim3(12, 512), 256, 0, stream>>>(ybf, wqkv, qkv_b, nullptr, qkvbf, 65536, 1536, 512);
  attn_mfma<<<1024, 256, 0, stream>>>(qkvbf, mmap, rpb, attno);
  gemm_nt<EPI_PROJ><<<dim3(4, 512), 256, 0, stream>>>(attno, wproj, proj_b, x, x1, 65536, 512, 512);
  ln_bf16<<<16384, 256, 0, stream>>>(x1, n2g, n2b, ybf);
  gemm_nt<EPI_GELU><<<dim3(16, 512), 256, 0, stream>>>(ybf, wfc1, fc1_b, nullptr, hbuf, 65536, 2048, 512);
  gemm_nt<EPI_FC2><<<dim3(4, 512), 256, 0, stream>>>(hbuf, wfc2, fc2_b, x1, out, 65536, 512, 2048);
}